// Round 4
// baseline (216.627 us; speedup 1.0000x reference)
//
#include <hip/hip_runtime.h>
#include <hip/hip_bf16.h>

#define BB 32
#define PP 8000
#define GG 100
#define PT 8100            // P + G
#define NSEL 512
#define POSCAP 128
#define OFF_LAB 65536      // 32*512*4
#define OFF_REG 81920      // OFF_LAB + 32*512
#define NTHR 1024
#define NWAVE 16

__device__ __forceinline__ unsigned rotl32(unsigned x, int r) {
  return (x << r) | (x >> (32 - r));
}

// Threefry-2x32, 20 rounds. JAX partitionable 32-bit stream for key(42):
// counter i (uint64) -> x0 = hi(i) = 0, x1 = lo(i) = i; key = (0, 42);
// bits = out0 ^ out1 ; uniform r = ((bits>>9)|0x3F800000).view(f32) - 1
__device__ __forceinline__ unsigned threefry_bits(unsigned ctr) {
  const unsigned k0 = 0u, k1 = 42u;
  const unsigned k2 = k0 ^ k1 ^ 0x1BD11BDAu;
  unsigned x0 = 0u + k0;    // counts_hi + key0
  unsigned x1 = ctr + k1;   // counts_lo + key1
#define TF4(a,b,c,d) \
  x0 += x1; x1 = rotl32(x1,(a)); x1 ^= x0; \
  x0 += x1; x1 = rotl32(x1,(b)); x1 ^= x0; \
  x0 += x1; x1 = rotl32(x1,(c)); x1 ^= x0; \
  x0 += x1; x1 = rotl32(x1,(d)); x1 ^= x0;
  TF4(13,15,26, 6)  x0 += k1; x1 += k2 + 1u;
  TF4(17,29,16,24)  x0 += k2; x1 += k0 + 2u;
  TF4(13,15,26, 6)  x0 += k0; x1 += k1 + 3u;
  TF4(17,29,16,24)  x0 += k1; x1 += k2 + 4u;
  TF4(13,15,26, 6)  x0 += k2; x1 += k0 + 5u;
#undef TF4
  return x0 ^ x1;
}

// One block per image. Output buffer is FLOAT32 (reference's dtype).
__global__ __launch_bounds__(NTHR) void roiheads_fused(
    const float* __restrict__ proposals,
    const float* __restrict__ gt_boxes,
    const int*   __restrict__ gt_labels,
    float* __restrict__ out)
{
  const int b = blockIdx.x;
  const int tid = threadIdx.x;
  const int lane = tid & 63;
  const int wid = tid >> 6;

  __shared__ float sg[GG * 4];
  __shared__ float sarea[GG];
  __shared__ int   slab[GG];
  __shared__ unsigned sp[PT];         // key(23b) | cls<<24
  __shared__ unsigned char smid[PT];  // clamped match idx (0..99)
  __shared__ unsigned redw[NWAVE];
  __shared__ unsigned wtie[NWAVE];
  __shared__ unsigned wsel[NWAVE];

  for (int g = tid; g < GG; g += NTHR) {
    const float* q = gt_boxes + ((size_t)b * GG + g) * 4;
    float q0 = q[0], q1 = q[1], q2 = q[2], q3 = q[3];
    sg[g * 4 + 0] = q0; sg[g * 4 + 1] = q1; sg[g * 4 + 2] = q2; sg[g * 4 + 3] = q3;
    sarea[g] = (q2 - q0) * (q3 - q1);      // same op order as reference
    slab[g] = gt_labels[b * GG + g];
  }
  __syncthreads();

  // ---- phase 1: IoU argmax + label + threefry key per proposal ----
  for (int t = tid; t < PT; t += NTHR) {
    float p0, p1, p2, p3;
    if (t < PP) {
      const float* pr = proposals + ((size_t)b * PP + t) * 4;
      p0 = pr[0]; p1 = pr[1]; p2 = pr[2]; p3 = pr[3];
    } else {
      const float* pr = gt_boxes + ((size_t)b * GG + (t - PP)) * 4;
      p0 = pr[0]; p1 = pr[1]; p2 = pr[2]; p3 = pr[3];
    }
    float area_p = (p2 - p0) * (p3 - p1);
    asm volatile("" : "+v"(area_p));       // block FMA contraction into sum

    float best = -1.0f;
    int bidx = 0;
    for (int g = 0; g < GG; ++g) {
      float q0 = sg[g*4+0], q1 = sg[g*4+1], q2 = sg[g*4+2], q3 = sg[g*4+3];
      float w = fminf(q2, p2) - fmaxf(q0, p0);
      float h = fminf(q3, p3) - fmaxf(q1, p1);
      w = fmaxf(w, 0.0f);
      h = fmaxf(h, 0.0f);
      float inter = w * h;
      asm volatile("" : "+v"(inter));      // block FMA contraction into union
      float uni = (sarea[g] + area_p) - inter;
      float iou = inter / uni;
      if (iou > best) { best = iou; bidx = g; }  // first-max == jnp argmax
    }

    int cls, m;
    if (best < 0.5f) { cls = 0; m = 0; }   // matched=-1 -> label 0, clamp idx 0
    else             { cls = slab[bidx]; m = bidx; }

    unsigned bits = threefry_bits((unsigned)(b * PT + t));
    sp[t] = (bits >> 9) | ((unsigned)cls << 24);
    smid[t] = (unsigned char)m;
  }
  __syncthreads();

  // ---- phase 2: top-k thresholds via binary search on the 23-bit key ----
  auto countFn = [&](int grp, unsigned theta, bool countAll) -> unsigned {
    unsigned c = 0;
    for (int t = tid; t < PT; t += NTHR) {
      unsigned v = sp[t];
      unsigned cls = v >> 24;
      bool memb = grp ? (cls >= 1u) : (cls == 0u);
      if (memb && (countAll || (v & 0x7FFFFFu) > theta)) c++;
    }
    for (int d = 32; d >= 1; d >>= 1) c += __shfl_down(c, d, 64);
    if (lane == 0) redw[wid] = c;
    __syncthreads();
    unsigned tot = 0;
    for (int w = 0; w < NWAVE; ++w) tot += redw[w];
    __syncthreads();
    return tot;
  };

  unsigned num_pos = countFn(1, 0, true);
  bool allP = (num_pos <= POSCAP);
  unsigned capP = allP ? num_pos : POSCAP;
  unsigned thetaP = 0, mP = 0;
  if (!allP) {
    unsigned lo = 0, hi = (1u << 23) - 1;
    while (lo < hi) {                      // smallest theta: #(key>theta) < cap
      unsigned mid = (lo + hi) >> 1;
      unsigned c = countFn(1, mid, false);
      if (c < POSCAP) hi = mid; else lo = mid + 1;
    }
    thetaP = lo;
    unsigned cgt = countFn(1, thetaP, false);
    mP = POSCAP - cgt;                     // # ties (key==theta) taken, index order
  }

  unsigned Kneg = NSEL - capP;
  unsigned num_neg = countFn(0, 0, true);
  bool allN = (num_neg <= Kneg);
  unsigned thetaN = 0, mN = 0;
  if (!allN) {
    unsigned lo = 0, hi = (1u << 23) - 1;
    while (lo < hi) {
      unsigned mid = (lo + hi) >> 1;
      unsigned c = countFn(0, mid, false);
      if (c < Kneg) hi = mid; else lo = mid + 1;
    }
    thetaN = lo;
    unsigned cgt = countFn(0, thetaN, false);
    mN = Kneg - cgt;
  }

  // ---- phase 3: stable compaction in ascending index order + epilogue ----
  unsigned runTP = 0, runTN = 0, runSel = 0;
  for (int base = 0; base < PT; base += NTHR) {
    int t = base + tid;
    bool valid = (t < PT);
    unsigned v = valid ? sp[t] : 0u;
    unsigned cls = v >> 24;
    unsigned key = v & 0x7FFFFFu;
    bool isP = valid && (cls >= 1u);
    bool isN = valid && (cls == 0u);
    bool hard = false, tp = false, tn = false;
    if (isP) { if (allP) hard = true; else if (key > thetaP) hard = true; else if (key == thetaP) tp = true; }
    if (isN) { if (allN) hard = true; else if (key > thetaN) hard = true; else if (key == thetaN) tn = true; }

    // scan tie flags (tp | tn<<16)
    unsigned pk = (tp ? 1u : 0u) | ((tn ? 1u : 0u) << 16);
    unsigned inc = pk;
    for (int d = 1; d < 64; d <<= 1) { unsigned o = __shfl_up(inc, d, 64); if (lane >= d) inc += o; }
    if (lane == 63) wtie[wid] = inc;
    __syncthreads();
    unsigned baseT = 0, totT = 0;
    for (int w = 0; w < NWAVE; ++w) { unsigned x = wtie[w]; if (w < wid) baseT += x; totT += x; }
    unsigned exclT = baseT + inc - pk;
    bool sel = hard;
    if (tp && (runTP + (exclT & 0xFFFFu)) < mP) sel = true;
    if (tn && (runTN + (exclT >> 16))    < mN) sel = true;
    __syncthreads();

    // scan final selected flags for stable output position
    unsigned sv = sel ? 1u : 0u;
    unsigned incS = sv;
    for (int d = 1; d < 64; d <<= 1) { unsigned o = __shfl_up(incS, d, 64); if (lane >= d) incS += o; }
    if (lane == 63) wsel[wid] = incS;
    __syncthreads();
    unsigned baseS = 0, totS = 0;
    for (int w = 0; w < NWAVE; ++w) { unsigned x = wsel[w]; if (w < wid) baseS += x; totS += x; }
    unsigned pos = runSel + baseS + incS - sv;

    if (sel && pos < NSEL) {
      float p0, p1, p2, p3;
      if (t < PP) {
        const float* pr = proposals + ((size_t)b * PP + t) * 4;
        p0 = pr[0]; p1 = pr[1]; p2 = pr[2]; p3 = pr[3];
      } else {
        const float* pr = gt_boxes + ((size_t)b * GG + (t - PP)) * 4;
        p0 = pr[0]; p1 = pr[1]; p2 = pr[2]; p3 = pr[3];
      }
      int m = smid[t];
      const float* gq = gt_boxes + ((size_t)b * GG + m) * 4;
      float g0 = gq[0], g1 = gq[1], g2 = gq[2], g3 = gq[3];

      size_t o1 = (size_t)b * NSEL + pos;
      out[o1 * 4 + 0] = p0;
      out[o1 * 4 + 1] = p1;
      out[o1 * 4 + 2] = p2;
      out[o1 * 4 + 3] = p3;
      out[OFF_LAB + o1] = (float)cls;

      float pw = p2 - p0, ph = p3 - p1;
      float px = p0 + 0.5f * pw, py = p1 + 0.5f * ph;
      float gw = g2 - g0, gh = g3 - g1;
      float gx = g0 + 0.5f * gw, gy = g1 + 0.5f * gh;
      size_t o2 = OFF_REG + o1 * 4;
      out[o2 + 0] = 10.0f * (gx - px) / pw;
      out[o2 + 1] = 10.0f * (gy - py) / ph;
      out[o2 + 2] = 5.0f * logf(gw / pw);
      out[o2 + 3] = 5.0f * logf(gh / ph);
    }

    runTP += totT & 0xFFFFu;
    runTN += totT >> 16;
    runSel += totS;
    __syncthreads();   // guard wtie/wsel reuse next chunk
  }
}

extern "C" void kernel_launch(void* const* d_in, const int* in_sizes, int n_in,
                              void* d_out, int out_size, void* d_ws, size_t ws_size,
                              hipStream_t stream) {
  const float* proposals = (const float*)d_in[0];
  const float* gt_boxes  = (const float*)d_in[1];
  const int*   gt_labels = (const int*)d_in[2];
  float* out = (float*)d_out;

  roiheads_fused<<<BB, NTHR, 0, stream>>>(proposals, gt_boxes, gt_labels, out);
}

// Round 5
// 75.164 us; speedup vs baseline: 2.8821x; 2.8821x over previous
//
#include <hip/hip_runtime.h>

#define BB 32
#define PP 8000
#define GG 100
#define PT 8100            // P + G
#define NSEL 512
#define POSCAP 128
#define OFF_LAB 65536      // 32*512*4
#define OFF_REG 81920      // OFF_LAB + 32*512
#define NT1 256
#define NT2 1024
#define NW2 16

__device__ __forceinline__ unsigned rotl32(unsigned x, int r) {
  return (x << r) | (x >> (32 - r));
}

// Threefry-2x32, 20 rounds. JAX partitionable 32-bit stream for key(42):
// counter i (uint64) -> x0 = hi(i)=0, x1 = lo(i)=i; key=(0,42); bits = out0^out1
__device__ __forceinline__ unsigned threefry_bits(unsigned ctr) {
  const unsigned k0 = 0u, k1 = 42u;
  const unsigned k2 = k0 ^ k1 ^ 0x1BD11BDAu;
  unsigned x0 = 0u + k0;
  unsigned x1 = ctr + k1;
#define TF4(a,b,c,d) \
  x0 += x1; x1 = rotl32(x1,(a)); x1 ^= x0; \
  x0 += x1; x1 = rotl32(x1,(b)); x1 ^= x0; \
  x0 += x1; x1 = rotl32(x1,(c)); x1 ^= x0; \
  x0 += x1; x1 = rotl32(x1,(d)); x1 ^= x0;
  TF4(13,15,26, 6)  x0 += k1; x1 += k2 + 1u;
  TF4(17,29,16,24)  x0 += k2; x1 += k0 + 2u;
  TF4(13,15,26, 6)  x0 += k0; x1 += k1 + 3u;
  TF4(17,29,16,24)  x0 += k1; x1 += k2 + 4u;
  TF4(13,15,26, 6)  x0 += k2; x1 += k0 + 5u;
#undef TF4
  return x0 ^ x1;
}

// Kernel 1: per (b,t): IoU argmax over G gts -> cls, midx, threefry key.
// Grid (32 chunks, 32 images) x 256 threads: all 256 CUs busy.
__global__ __launch_bounds__(NT1) void label_kernel(
    const float* __restrict__ proposals,
    const float* __restrict__ gt_boxes,
    const int*   __restrict__ gt_labels,
    unsigned*    __restrict__ packed,
    unsigned char* __restrict__ midxv)
{
  const int b = blockIdx.y;
  const int t = blockIdx.x * NT1 + threadIdx.x;

  __shared__ float sgx[GG], sgy[GG], sgX[GG], sgY[GG], sarea[GG];
  __shared__ int   slab[GG];
  if (threadIdx.x < GG) {
    int g = threadIdx.x;
    const float* q = gt_boxes + ((size_t)b * GG + g) * 4;
    float q0 = q[0], q1 = q[1], q2 = q[2], q3 = q[3];
    sgx[g] = q0; sgy[g] = q1; sgX[g] = q2; sgY[g] = q3;
    sarea[g] = (q2 - q0) * (q3 - q1);      // same op order as reference
    slab[g] = gt_labels[b * GG + g];
  }
  __syncthreads();
  if (t >= PT) return;

  const float* pr = (t < PP) ? proposals + ((size_t)b * PP + t) * 4
                             : gt_boxes  + ((size_t)b * GG + (t - PP)) * 4;
  float p0 = pr[0], p1 = pr[1], p2 = pr[2], p3 = pr[3];
  float area_p = (p2 - p0) * (p3 - p1);
  asm volatile("" : "+v"(area_p));         // block FMA contraction into sum

  float best = -1.0f;
  int bidx = 0;
  for (int g = 0; g < GG; ++g) {
    float w = fminf(sgX[g], p2) - fmaxf(sgx[g], p0);
    float h = fminf(sgY[g], p3) - fmaxf(sgy[g], p1);
    w = fmaxf(w, 0.0f);
    h = fmaxf(h, 0.0f);
    float inter = w * h;
    asm volatile("" : "+v"(inter));        // block FMA contraction into union
    float uni = (sarea[g] + area_p) - inter;
    float iou = inter / uni;
    if (iou > best) { best = iou; bidx = g; }   // first-max == jnp argmax
  }

  int cls, m;
  if (best < 0.5f) { cls = 0; m = 0; }
  else             { cls = slab[bidx]; m = bidx; }

  unsigned bits = threefry_bits((unsigned)(b * PT + t));
  packed[(size_t)b * PT + t] = (bits >> 9) | ((unsigned)cls << 24);
  midxv[(size_t)b * PT + t] = (unsigned char)m;
}

// Kernel 2: one block per image. Fused dual binary search (pos & neg counted
// in the same scan, packed cntP | cntN<<16), then stable compaction.
__global__ __launch_bounds__(NT2) void select_kernel(
    const float*    __restrict__ proposals,
    const float*    __restrict__ gt_boxes,
    const unsigned* __restrict__ packed,
    const unsigned char* __restrict__ midxv,
    float* __restrict__ out)
{
  const int b = blockIdx.x;
  const int tid = threadIdx.x;
  const int lane = tid & 63;
  const int wid = tid >> 6;

  __shared__ unsigned sp[PT];
  __shared__ unsigned redw[NW2], wtie[NW2], wsel[NW2];

  for (int t = tid; t < PT; t += NT2) sp[t] = packed[(size_t)b * PT + t];
  __syncthreads();

  auto reduceAll = [&](unsigned c) -> unsigned {
    for (int d = 32; d >= 1; d >>= 1) c += __shfl_down(c, d, 64);
    if (lane == 0) redw[wid] = c;
    __syncthreads();
    unsigned tot = 0;
#pragma unroll
    for (int w = 0; w < NW2; ++w) tot += redw[w];
    __syncthreads();
    return tot;
  };

  // pass 0: population counts (pos | neg<<16)
  unsigned c0 = 0;
  for (int t = tid; t < PT; t += NT2) {
    unsigned cls = sp[t] >> 24;
    c0 += (cls >= 1u ? 1u : 0u) | ((cls == 0u ? 1u : 0u) << 16);
  }
  unsigned tots = reduceAll(c0);
  unsigned num_pos = tots & 0xFFFFu, num_neg = tots >> 16;
  bool allP = (num_pos <= POSCAP);
  unsigned capP = allP ? num_pos : POSCAP;
  unsigned Kneg = NSEL - capP;
  bool allN = (num_neg <= Kneg);

  // 23 lockstep iterations: both searches share each scan.
  // invariant: find smallest theta with #(key > theta) < cap
  unsigned loP = 0, hiP = (1u << 23) - 1;
  unsigned loN = 0, hiN = (1u << 23) - 1;
  for (int it = 0; it < 23; ++it) {
    unsigned midP = (loP + hiP) >> 1, midN = (loN + hiN) >> 1;
    unsigned c = 0;
    for (int t = tid; t < PT; t += NT2) {
      unsigned v = sp[t];
      unsigned cls = v >> 24;
      unsigned key = v & 0x7FFFFFu;
      c += ((cls >= 1u && key > midP) ? 1u : 0u)
         | (((cls == 0u && key > midN) ? 1u : 0u) << 16);
    }
    unsigned tot = reduceAll(c);
    if ((tot & 0xFFFFu) < POSCAP) hiP = midP; else loP = midP + 1;
    if ((tot >> 16)     < Kneg)   hiN = midN; else loN = midN + 1;
  }
  unsigned thetaP = loP, thetaN = loN;

  // tie pass: #(key > theta) for both groups
  unsigned c1 = 0;
  for (int t = tid; t < PT; t += NT2) {
    unsigned v = sp[t];
    unsigned cls = v >> 24;
    unsigned key = v & 0x7FFFFFu;
    c1 += ((cls >= 1u && key > thetaP) ? 1u : 0u)
        | (((cls == 0u && key > thetaN) ? 1u : 0u) << 16);
  }
  unsigned cg = reduceAll(c1);
  unsigned mP = allP ? 0u : (POSCAP - (cg & 0xFFFFu));   // ties taken, index order
  unsigned mN = allN ? 0u : (Kneg   - (cg >> 16));

  // ---- stable compaction in ascending index order + epilogue ----
  unsigned runTP = 0, runTN = 0, runSel = 0;
  for (int base = 0; base < PT; base += NT2) {
    int t = base + tid;
    bool valid = (t < PT);
    unsigned v = valid ? sp[t] : 0u;
    unsigned cls = v >> 24;
    unsigned key = v & 0x7FFFFFu;
    bool isP = valid && (cls >= 1u);
    bool isN = valid && (cls == 0u);
    bool hard = false, tp = false, tn = false;
    if (isP) { if (allP) hard = true; else if (key > thetaP) hard = true; else if (key == thetaP) tp = true; }
    if (isN) { if (allN) hard = true; else if (key > thetaN) hard = true; else if (key == thetaN) tn = true; }

    unsigned pk = (tp ? 1u : 0u) | ((tn ? 1u : 0u) << 16);
    unsigned inc = pk;
    for (int d = 1; d < 64; d <<= 1) { unsigned o = __shfl_up(inc, d, 64); if (lane >= d) inc += o; }
    if (lane == 63) wtie[wid] = inc;
    __syncthreads();
    unsigned baseT = 0, totT = 0;
#pragma unroll
    for (int w = 0; w < NW2; ++w) { unsigned x = wtie[w]; if (w < wid) baseT += x; totT += x; }
    unsigned exclT = baseT + inc - pk;
    bool sel = hard;
    if (tp && (runTP + (exclT & 0xFFFFu)) < mP) sel = true;
    if (tn && (runTN + (exclT >> 16))    < mN) sel = true;
    __syncthreads();

    unsigned sv = sel ? 1u : 0u;
    unsigned incS = sv;
    for (int d = 1; d < 64; d <<= 1) { unsigned o = __shfl_up(incS, d, 64); if (lane >= d) incS += o; }
    if (lane == 63) wsel[wid] = incS;
    __syncthreads();
    unsigned baseS = 0, totS = 0;
#pragma unroll
    for (int w = 0; w < NW2; ++w) { unsigned x = wsel[w]; if (w < wid) baseS += x; totS += x; }
    unsigned pos = runSel + baseS + incS - sv;

    if (sel && pos < NSEL) {
      const float* pr = (t < PP) ? proposals + ((size_t)b * PP + t) * 4
                                 : gt_boxes  + ((size_t)b * GG + (t - PP)) * 4;
      float p0 = pr[0], p1 = pr[1], p2 = pr[2], p3 = pr[3];
      int m = midxv[(size_t)b * PT + t];
      const float* gq = gt_boxes + ((size_t)b * GG + m) * 4;
      float g0 = gq[0], g1 = gq[1], g2 = gq[2], g3 = gq[3];

      size_t o1 = (size_t)b * NSEL + pos;
      out[o1 * 4 + 0] = p0;
      out[o1 * 4 + 1] = p1;
      out[o1 * 4 + 2] = p2;
      out[o1 * 4 + 3] = p3;
      out[OFF_LAB + o1] = (float)cls;

      float pw = p2 - p0, ph = p3 - p1;
      float px = p0 + 0.5f * pw, py = p1 + 0.5f * ph;
      float gw = g2 - g0, gh = g3 - g1;
      float gx = g0 + 0.5f * gw, gy = g1 + 0.5f * gh;
      size_t o2 = OFF_REG + o1 * 4;
      out[o2 + 0] = 10.0f * (gx - px) / pw;
      out[o2 + 1] = 10.0f * (gy - py) / ph;
      out[o2 + 2] = 5.0f * logf(gw / pw);
      out[o2 + 3] = 5.0f * logf(gh / ph);
    }

    runTP += totT & 0xFFFFu;
    runTN += totT >> 16;
    runSel += totS;
    __syncthreads();
  }
}

extern "C" void kernel_launch(void* const* d_in, const int* in_sizes, int n_in,
                              void* d_out, int out_size, void* d_ws, size_t ws_size,
                              hipStream_t stream) {
  const float* proposals = (const float*)d_in[0];
  const float* gt_boxes  = (const float*)d_in[1];
  const int*   gt_labels = (const int*)d_in[2];
  float* out = (float*)d_out;

  unsigned* packed = (unsigned*)d_ws;
  unsigned char* midxv = (unsigned char*)d_ws + (size_t)BB * PT * sizeof(unsigned);

  dim3 g1((PT + NT1 - 1) / NT1, BB);
  label_kernel<<<g1, NT1, 0, stream>>>(proposals, gt_boxes, gt_labels, packed, midxv);
  select_kernel<<<BB, NT2, 0, stream>>>(proposals, gt_boxes, packed, midxv, out);
}

// Round 6
// 45.929 us; speedup vs baseline: 4.7166x; 1.6365x over previous
//
#include <hip/hip_runtime.h>

#define BB 32
#define PP 8000
#define GG 100
#define PT 8100            // P + G
#define NSEL 512
#define POSCAP 128
#define OFF_LAB 65536      // 32*512*4
#define OFF_REG 81920      // OFF_LAB + 32*512
#define NT1 256
#define NT2 1024
#define NW2 16
#define HB 4096            // histogram bins (top 12 of 23 key bits)
#define GCAP 512           // gather buffer cap per group

__device__ __forceinline__ unsigned rotl32(unsigned x, int r) {
  return (x << r) | (x >> (32 - r));
}

// Threefry-2x32, 20 rounds. JAX partitionable 32-bit stream for key(42):
// counter i (uint64) -> x0 = hi(i)=0, x1 = lo(i)=i; key=(0,42); bits = out0^out1
__device__ __forceinline__ unsigned threefry_bits(unsigned ctr) {
  const unsigned k0 = 0u, k1 = 42u;
  const unsigned k2 = k0 ^ k1 ^ 0x1BD11BDAu;
  unsigned x0 = 0u + k0;
  unsigned x1 = ctr + k1;
#define TF4(a,b,c,d) \
  x0 += x1; x1 = rotl32(x1,(a)); x1 ^= x0; \
  x0 += x1; x1 = rotl32(x1,(b)); x1 ^= x0; \
  x0 += x1; x1 = rotl32(x1,(c)); x1 ^= x0; \
  x0 += x1; x1 = rotl32(x1,(d)); x1 ^= x0;
  TF4(13,15,26, 6)  x0 += k1; x1 += k2 + 1u;
  TF4(17,29,16,24)  x0 += k2; x1 += k0 + 2u;
  TF4(13,15,26, 6)  x0 += k0; x1 += k1 + 3u;
  TF4(17,29,16,24)  x0 += k1; x1 += k2 + 4u;
  TF4(13,15,26, 6)  x0 += k2; x1 += k0 + 5u;
#undef TF4
  return x0 ^ x1;
}

// Kernel 1: per (b,t): IoU argmax over G gts -> cls, midx, threefry key.
__global__ __launch_bounds__(NT1) void label_kernel(
    const float* __restrict__ proposals,
    const float* __restrict__ gt_boxes,
    const int*   __restrict__ gt_labels,
    unsigned*    __restrict__ packed,
    unsigned char* __restrict__ midxv)
{
  const int b = blockIdx.y;
  const int t = blockIdx.x * NT1 + threadIdx.x;

  __shared__ float sgx[GG], sgy[GG], sgX[GG], sgY[GG], sarea[GG];
  __shared__ int   slab[GG];
  if (threadIdx.x < GG) {
    int g = threadIdx.x;
    const float* q = gt_boxes + ((size_t)b * GG + g) * 4;
    float q0 = q[0], q1 = q[1], q2 = q[2], q3 = q[3];
    sgx[g] = q0; sgy[g] = q1; sgX[g] = q2; sgY[g] = q3;
    sarea[g] = (q2 - q0) * (q3 - q1);      // same op order as reference
    slab[g] = gt_labels[b * GG + g];
  }
  __syncthreads();
  if (t >= PT) return;

  const float* pr = (t < PP) ? proposals + ((size_t)b * PP + t) * 4
                             : gt_boxes  + ((size_t)b * GG + (t - PP)) * 4;
  float p0 = pr[0], p1 = pr[1], p2 = pr[2], p3 = pr[3];
  float area_p = (p2 - p0) * (p3 - p1);
  asm volatile("" : "+v"(area_p));         // block FMA contraction into sum

  float best = -1.0f;
  int bidx = 0;
  for (int g = 0; g < GG; ++g) {
    float w = fminf(sgX[g], p2) - fmaxf(sgx[g], p0);
    float h = fminf(sgY[g], p3) - fmaxf(sgy[g], p1);
    w = fmaxf(w, 0.0f);
    h = fmaxf(h, 0.0f);
    float inter = w * h;
    asm volatile("" : "+v"(inter));        // block FMA contraction into union
    float uni = (sarea[g] + area_p) - inter;
    float iou = inter / uni;
    if (iou > best) { best = iou; bidx = g; }   // first-max == jnp argmax
  }

  int cls, m;
  if (best < 0.5f) { cls = 0; m = 0; }
  else             { cls = slab[bidx]; m = bidx; }

  unsigned bits = threefry_bits((unsigned)(b * PT + t));
  packed[(size_t)b * PT + t] = (bits >> 9) | ((unsigned)cls << 24);
  midxv[(size_t)b * PT + t] = (unsigned char)m;
}

// Kernel 2: one block per image. Histogram threshold-finder (exact, tie-aware)
// + single-pass stable compaction. ~13 block barriers total.
__global__ __launch_bounds__(NT2) void select_kernel(
    const float*    __restrict__ proposals,
    const float*    __restrict__ gt_boxes,
    const unsigned* __restrict__ packed,
    const unsigned char* __restrict__ midxv,
    float* __restrict__ out)
{
  const int b = blockIdx.x;
  const int tid = threadIdx.x;
  const int lane = tid & 63;
  const int wid = tid >> 6;

  __shared__ unsigned sp[PT];
  __shared__ unsigned hist[HB];        // pos count low16 | neg count high16
  __shared__ unsigned waveTot[NW2];
  __shared__ unsigned wsum[NW2];
  __shared__ unsigned gbufP[GCAP], gbufN[GCAP];
  __shared__ unsigned sBin[2], sAbove[2], sTheta[2], sM[2], sCnt[2];

  // 1: load keys, zero histogram
  for (int t = tid; t < PT; t += NT2) sp[t] = packed[(size_t)b * PT + t];
#pragma unroll
  for (int i = 0; i < HB / NT2; ++i) hist[tid + i * NT2] = 0u;
  __syncthreads();

  // 2: histogram on top 12 bits of the 23-bit key
  for (int t = tid; t < PT; t += NT2) {
    unsigned v = sp[t];
    unsigned bin = (v & 0x7FFFFFu) >> 11;
    atomicAdd(&hist[bin], (v >> 24) >= 1u ? 1u : 0x10000u);
  }
  __syncthreads();

  // 3: block suffix-scan over per-thread 4-bin sums (packed)
  unsigned local = 0;
#pragma unroll
  for (int j = 0; j < 4; ++j) local += hist[tid * 4 + j];
  unsigned suf = local;
  for (int d = 1; d < 64; d <<= 1) {
    unsigned o = __shfl_down(suf, d, 64);
    if (lane + d < 64) suf += o;
  }
  if (lane == 0) waveTot[wid] = suf;     // whole-wave sum
  __syncthreads();

  // 4: totals, caps, locate threshold bins; zero gather counters
  unsigned totAll = 0, waveAfter = 0;
#pragma unroll
  for (int w = 0; w < NW2; ++w) { unsigned x = waveTot[w]; totAll += x; if (w > wid) waveAfter += x; }
  unsigned num_pos = totAll & 0xFFFFu, num_neg = totAll >> 16;
  bool allP = (num_pos <= POSCAP);
  unsigned capP = allP ? num_pos : POSCAP;
  unsigned Kneg = NSEL - capP;
  bool allN = (num_neg <= Kneg);
  unsigned sumAfter = waveAfter + (suf - local);  // threads strictly after me
  {
    unsigned aP = sumAfter & 0xFFFFu, aN = sumAfter >> 16;
#pragma unroll
    for (int j = 3; j >= 0; --j) {
      unsigned hc = hist[tid * 4 + j];
      unsigned hp = hc & 0xFFFFu, hn = hc >> 16;
      if (!allP && aP < POSCAP && aP + hp >= POSCAP) { sBin[0] = tid * 4 + j; sAbove[0] = aP; }
      if (!allN && aN < Kneg   && aN + hn >= Kneg)   { sBin[1] = tid * 4 + j; sAbove[1] = aN; }
      aP += hp; aN += hn;
    }
  }
  if (tid < 2) sCnt[tid] = 0u;
  __syncthreads();

  // 5: gather members of the threshold bins
  unsigned binP = sBin[0], binN = sBin[1];
  for (int t = tid; t < PT; t += NT2) {
    unsigned v = sp[t];
    unsigned key = v & 0x7FFFFFu;
    bool isP = (v >> 24) >= 1u;
    if (!allP && isP && (key >> 11) == binP) {
      unsigned i = atomicAdd(&sCnt[0], 1u);
      if (i < GCAP) gbufP[i] = key;
    }
    if (!allN && !isP && (key >> 11) == binN) {
      unsigned i = atomicAdd(&sCnt[1], 1u);
      if (i < GCAP) gbufN[i] = key;
    }
  }
  __syncthreads();

  // 6: exact in-bin rank resolve (wave 0: pos, wave 1: neg)
  if (wid == 0 && !allP) {
    int n = min((int)sCnt[0], GCAP);
    unsigned above = sAbove[0];
    unsigned r = POSCAP - above;       // 1-indexed rank within bin
    for (int i = lane; i < n; i += 64) {
      unsigned ki = gbufP[i];
      unsigned gt = 0, ge = 0;
      for (int j = 0; j < n; ++j) { unsigned kj = gbufP[j]; gt += (kj > ki); ge += (kj >= ki); }
      if (gt < r && ge >= r) { sTheta[0] = ki; sM[0] = POSCAP - (above + gt); }
    }
  }
  if (wid == 1 && !allN) {
    int n = min((int)sCnt[1], GCAP);
    unsigned above = sAbove[1];
    unsigned r = Kneg - above;
    for (int i = lane; i < n; i += 64) {
      unsigned ki = gbufN[i];
      unsigned gt = 0, ge = 0;
      for (int j = 0; j < n; ++j) { unsigned kj = gbufN[j]; gt += (kj > ki); ge += (kj >= ki); }
      if (gt < r && ge >= r) { sTheta[1] = ki; sM[1] = Kneg - (above + gt); }
    }
  }
  __syncthreads();

  unsigned thetaP = allP ? 0u : sTheta[0];
  unsigned mP     = allP ? 0u : sM[0];
  unsigned thetaN = allN ? 0u : sTheta[1];
  unsigned mN     = allN ? 0u : sM[1];

  // 7: single-pass stable compaction — thread owns 8 consecutive indices
  auto blockExclScan = [&](unsigned val) -> unsigned {
    unsigned inc = val;
    for (int d = 1; d < 64; d <<= 1) { unsigned o = __shfl_up(inc, d, 64); if (lane >= d) inc += o; }
    if (lane == 63) wsum[wid] = inc;
    __syncthreads();
    unsigned base = 0;
#pragma unroll
    for (int w = 0; w < NW2; ++w) { if (w < wid) base += wsum[w]; }
    __syncthreads();
    return base + inc - val;   // exclusive prefix
  };

  const int t0 = tid * 8;
  unsigned hardM = 0, tpM = 0, tnM = 0;
  unsigned tieCnt = 0;
#pragma unroll
  for (int j = 0; j < 8; ++j) {
    int t = t0 + j;
    if (t < PT) {
      unsigned v = sp[t];
      unsigned key = v & 0x7FFFFFu;
      if ((v >> 24) >= 1u) {
        if (allP || key > thetaP) hardM |= 1u << j;
        else if (key == thetaP)   { tpM |= 1u << j; tieCnt += 1u; }
      } else {
        if (allN || key > thetaN) hardM |= 1u << j;
        else if (key == thetaN)   { tnM |= 1u << j; tieCnt += 0x10000u; }
      }
    }
  }
  unsigned tieBase = blockExclScan(tieCnt);
  unsigned runP = tieBase & 0xFFFFu, runN = tieBase >> 16;
  unsigned selM = 0, selCnt = 0;
#pragma unroll
  for (int j = 0; j < 8; ++j) {
    bool s = false;
    if (hardM & (1u << j)) s = true;
    else if (tpM & (1u << j)) { s = (runP < mP); runP++; }
    else if (tnM & (1u << j)) { s = (runN < mN); runN++; }
    if (s) { selM |= 1u << j; selCnt++; }
  }
  unsigned pos = blockExclScan(selCnt);

#pragma unroll
  for (int j = 0; j < 8; ++j) {
    if (selM & (1u << j)) {
      int t = t0 + j;
      unsigned cls = sp[t] >> 24;
      const float* pr = (t < PP) ? proposals + ((size_t)b * PP + t) * 4
                                 : gt_boxes  + ((size_t)b * GG + (t - PP)) * 4;
      float p0 = pr[0], p1 = pr[1], p2 = pr[2], p3 = pr[3];
      int m = midxv[(size_t)b * PT + t];
      const float* gq = gt_boxes + ((size_t)b * GG + m) * 4;
      float g0 = gq[0], g1 = gq[1], g2 = gq[2], g3 = gq[3];

      size_t o1 = (size_t)b * NSEL + pos;
      out[o1 * 4 + 0] = p0;
      out[o1 * 4 + 1] = p1;
      out[o1 * 4 + 2] = p2;
      out[o1 * 4 + 3] = p3;
      out[OFF_LAB + o1] = (float)cls;

      float pw = p2 - p0, ph = p3 - p1;
      float px = p0 + 0.5f * pw, py = p1 + 0.5f * ph;
      float gw = g2 - g0, gh = g3 - g1;
      float gx = g0 + 0.5f * gw, gy = g1 + 0.5f * gh;
      size_t o2 = OFF_REG + o1 * 4;
      out[o2 + 0] = 10.0f * (gx - px) / pw;
      out[o2 + 1] = 10.0f * (gy - py) / ph;
      out[o2 + 2] = 5.0f * logf(gw / pw);
      out[o2 + 3] = 5.0f * logf(gh / ph);
      pos++;
    }
  }
}

extern "C" void kernel_launch(void* const* d_in, const int* in_sizes, int n_in,
                              void* d_out, int out_size, void* d_ws, size_t ws_size,
                              hipStream_t stream) {
  const float* proposals = (const float*)d_in[0];
  const float* gt_boxes  = (const float*)d_in[1];
  const int*   gt_labels = (const int*)d_in[2];
  float* out = (float*)d_out;

  unsigned* packed = (unsigned*)d_ws;
  unsigned char* midxv = (unsigned char*)d_ws + (size_t)BB * PT * sizeof(unsigned);

  dim3 g1((PT + NT1 - 1) / NT1, BB);
  label_kernel<<<g1, NT1, 0, stream>>>(proposals, gt_boxes, gt_labels, packed, midxv);
  select_kernel<<<BB, NT2, 0, stream>>>(proposals, gt_boxes, packed, midxv, out);
}